// Round 7
// baseline (60.339 us; speedup 1.0000x reference)
//
#include <hip/hip_runtime.h>
#include <hip/hip_bf16.h>

typedef __attribute__((ext_vector_type(8))) short bf16x8;
typedef __attribute__((ext_vector_type(4))) float f32x4;

#define NB   4
#define NN   2048
#define FIN  256
#define FOUT 128
#define SPLIT 4
#define JCH  (NN / SPLIT)      // 512 j per block
#define NSTEP (JCH / 64)       // 8 steps of 64 j

__device__ __forceinline__ unsigned short f2bf(float f) {
    unsigned int u = __builtin_bit_cast(unsigned int, f);
    u += 0x7fffu + ((u >> 16) & 1u);
    return (unsigned short)(u >> 16);
}

// ---------------- Kernel 0: WT[o][k] bf16 from W[k][o] f32 ----------------
__global__ __launch_bounds__(256) void k_wt(const float* __restrict__ W,
                                            unsigned short* __restrict__ WT) {
    int idx = blockIdx.x * 256 + threadIdx.x;      // 32768 = 128*256
    int k = idx & 255, o = idx >> 8;
    WT[idx] = f2bf(W[k * FOUT + o]);
}

// ---------------- Kernel 1: Wh = h@W (MFMA), writes WhT bf16 + s1,s2 ------
__global__ __launch_bounds__(256) void k_wh(const float* __restrict__ h,
                                            const float* __restrict__ a,
                                            const unsigned short* __restrict__ WT,
                                            unsigned short* __restrict__ WhT,
                                            float* __restrict__ s1,
                                            float* __restrict__ s2) {
    __shared__ unsigned short hs[16][264];
    __shared__ float s1w[4][16], s2w[4][16];
    int t = threadIdx.x, blk = blockIdx.x;
    int nglob0 = blk * 16;
    int b = nglob0 >> 11;

    const float4* h4 = (const float4*)h + (size_t)blk * 1024;
    #pragma unroll
    for (int i = 0; i < 4; ++i) {
        int idx = i * 256 + t;
        float4 v = h4[idx];
        int row = idx >> 6, c4 = (idx & 63) * 4;
        unsigned int lo = (unsigned int)f2bf(v.x) | ((unsigned int)f2bf(v.y) << 16);
        unsigned int hi = (unsigned int)f2bf(v.z) | ((unsigned int)f2bf(v.w) << 16);
        *(uint2*)&hs[row][c4] = make_uint2(lo, hi);
    }
    __syncthreads();

    int w = t >> 6, l = t & 63, lr = l & 15, lk = l >> 4;
    float a1v[2], a2v[2];
    #pragma unroll
    for (int j = 0; j < 2; ++j) {
        a1v[j] = a[(w * 2 + j) * 16 + lr];
        a2v[j] = a[FOUT + (w * 2 + j) * 16 + lr];
    }
    f32x4 acc[2] = {{0.f,0.f,0.f,0.f},{0.f,0.f,0.f,0.f}};

    #pragma unroll
    for (int kk = 0; kk < 8; ++kk) {
        int k0 = kk * 32;
        bf16x8 af = *(const bf16x8*)&hs[lr][k0 + lk * 8];
        #pragma unroll
        for (int j = 0; j < 2; ++j) {
            bf16x8 bf = *(const bf16x8*)(WT + ((w * 2 + j) * 16 + lr) * 256 + k0 + lk * 8);
            acc[j] = __builtin_amdgcn_mfma_f32_16x16x32_bf16(af, bf, acc[j], 0, 0, 0);
        }
    }

    int nn0 = (nglob0 & 2047) + lk * 4;
    float v1[4] = {0.f,0.f,0.f,0.f}, v2[4] = {0.f,0.f,0.f,0.f};
    #pragma unroll
    for (int j = 0; j < 2; ++j) {
        float x0 = acc[j][0], x1 = acc[j][1], x2 = acc[j][2], x3 = acc[j][3];
        ushort4 pk;
        pk.x = f2bf(x0); pk.y = f2bf(x1); pk.z = f2bf(x2); pk.w = f2bf(x3);
        *(ushort4*)(WhT + (size_t)(b * FOUT + (w * 2 + j) * 16 + lr) * NN + nn0) = pk;
        v1[0] += x0 * a1v[j]; v1[1] += x1 * a1v[j]; v1[2] += x2 * a1v[j]; v1[3] += x3 * a1v[j];
        v2[0] += x0 * a2v[j]; v2[1] += x1 * a2v[j]; v2[2] += x2 * a2v[j]; v2[3] += x3 * a2v[j];
    }
    #pragma unroll
    for (int m = 1; m < 16; m <<= 1) {
        #pragma unroll
        for (int r = 0; r < 4; ++r) {
            v1[r] += __shfl_xor(v1[r], m);
            v2[r] += __shfl_xor(v2[r], m);
        }
    }
    if (lr == 0) {
        #pragma unroll
        for (int r = 0; r < 4; ++r) {
            s1w[w][lk * 4 + r] = v1[r];
            s2w[w][lk * 4 + r] = v2[r];
        }
    }
    __syncthreads();
    if (t < 16) {
        s1[nglob0 + t] = s1w[0][t] + s1w[1][t] + s1w[2][t] + s1w[3][t];
        s2[nglob0 + t] = s2w[0][t] + s2w[1][t] + s2w[2][t] + s2w[3][t];
    }
}

// ---------------- Kernel 2: partial attention, int4 adj prologue ----------
// grid = 2048 blocks x 256 thr; block: 16 rows x 512 j.
// Prologue: 8 independent dwordx4 loads/lane (16 B/lane — the only load
// width measured at >6 TB/s on gfx950), each 1 KB/wave contiguous; packed
// ballot-free into a 2 KB LDS nibble table. Loop: lgkmcnt-only barrier so
// the L2-resident WhT prefetches are never vmcnt-drained.
__global__ __launch_bounds__(256) void k_attn_part(const int* __restrict__ adj,
                                                   const unsigned short* __restrict__ WhT,
                                                   const float* __restrict__ s1,
                                                   const float* __restrict__ s2,
                                                   float* __restrict__ num,
                                                   float* __restrict__ Zp) {
    __shared__ unsigned short Ps[2][16][72];       // P tile bf16, 2 slots
    __shared__ unsigned char nibS[16][128];        // adj nibbles: [row][j/4]
    __shared__ float s2S[JCH];
    __shared__ float hS[16][132];

    int t = threadIdx.x, w = t >> 6, l = t & 63, lr = l & 15, lk = l >> 4;
    int bi = blockIdx.x;
    int part = bi >> 9;                            // 0..3
    int rem  = bi & 511;
    int b    = rem >> 7;
    int i0   = (rem & 127) * 16;
    int j0   = part * JCH;
    int rowA = t >> 4, kA = (t & 15) * 4;          // kA = j-offset in step

    // ---- prologue: adj -> nibbles via int4; stage s2 ----
    {
        int row0 = w * 4;                          // wave owns 4 rows
        const int* aBase = adj + ((size_t)(b * NN) + i0 + row0) * NN + j0;
        int4 v[8];
        #pragma unroll
        for (int r = 0; r < 4; ++r)
            #pragma unroll
            for (int hf = 0; hf < 2; ++hf)
                v[r * 2 + hf] = *(const int4*)(aBase + (size_t)r * NN + hf * 256 + l * 4);
        #pragma unroll
        for (int r = 0; r < 4; ++r)
            #pragma unroll
            for (int hf = 0; hf < 2; ++hf) {
                int4 q = v[r * 2 + hf];
                unsigned char nb = (unsigned char)((q.x > 0) | ((q.y > 0) << 1) |
                                                   ((q.z > 0) << 2) | ((q.w > 0) << 3));
                nibS[row0 + r][hf * 64 + l] = nb;
            }
        if (t < 128) ((float4*)s2S)[t] = ((const float4*)(s2 + b * NN + j0))[t];
    }
    float s1r = s1[b * NN + i0 + rowA];

    int obase = w * 32;
    const unsigned short* Bb = WhT + (size_t)(b * FOUT + obase + lr) * NN + j0 + lk * 8;

    f32x4 acc0 = {0.f,0.f,0.f,0.f}, acc1 = {0.f,0.f,0.f,0.f};
    float zacc = 0.f;

    // software prefetch of step 0 B-fragments (L2-resident)
    bf16x8 nb00 = *(const bf16x8*)(Bb);
    bf16x8 nb01 = *(const bf16x8*)(Bb + 32);
    bf16x8 nb10 = *(const bf16x8*)(Bb + 16 * NN);
    bf16x8 nb11 = *(const bf16x8*)(Bb + 16 * NN + 32);

    __syncthreads();                               // nibS/s2S visible

    for (int step = 0; step < NSTEP; ++step) {
        int slot = step & 1;
        bf16x8 b00 = nb00, b01 = nb01, b10 = nb10, b11 = nb11;
        if (step < NSTEP - 1) {                    // prefetch step+1 B (L2)
            const unsigned short* Bn = Bb + (step + 1) * 64;
            nb00 = *(const bf16x8*)(Bn);
            nb01 = *(const bf16x8*)(Bn + 32);
            nb10 = *(const bf16x8*)(Bn + 16 * NN);
            nb11 = *(const bf16x8*)(Bn + 16 * NN + 32);
        }

        // ---- phase A: build P tile (16 x 64) from LDS nibbles + s2 ----
        {
            unsigned int nib = nibS[rowA][step * 16 + (t & 15)];
            float4 svc = *(const float4*)&s2S[step * 64 + kA];
            float ss[4] = {svc.x, svc.y, svc.z, svc.w};
            unsigned short u[4];
            #pragma unroll
            for (int i = 0; i < 4; ++i) {
                float tt  = s1r + ss[i];
                float lrl = fmaxf(tt, 0.2f * tt);  // LeakyReLU
                float pp  = ((nib >> i) & 1u) ? __expf(lrl) : 0.f;
                zacc += pp;
                u[i] = f2bf(pp);
            }
            unsigned int lo = (unsigned int)u[0] | ((unsigned int)u[1] << 16);
            unsigned int hi = (unsigned int)u[2] | ((unsigned int)u[3] << 16);
            *(uint2*)&Ps[slot][rowA][kA] = make_uint2(lo, hi);
        }
        // LDS-write visibility only; keep B prefetches in flight
        asm volatile("s_waitcnt lgkmcnt(0)" ::: "memory");
        __builtin_amdgcn_s_barrier();

        // ---- phase B: 4 MFMAs ----
        const unsigned short* pr = &Ps[slot][lr][lk * 8];
        bf16x8 a0 = *(const bf16x8*)pr;
        bf16x8 a1 = *(const bf16x8*)(pr + 32);
        acc0 = __builtin_amdgcn_mfma_f32_16x16x32_bf16(a0, b00, acc0, 0, 0, 0);
        acc0 = __builtin_amdgcn_mfma_f32_16x16x32_bf16(a1, b01, acc0, 0, 0, 0);
        acc1 = __builtin_amdgcn_mfma_f32_16x16x32_bf16(a0, b10, acc1, 0, 0, 0);
        acc1 = __builtin_amdgcn_mfma_f32_16x16x32_bf16(a1, b11, acc1, 0, 0, 0);
    }

    // ---- Z partial reduction (16 lanes per row) ----
    #pragma unroll
    for (int m = 1; m < 16; m <<= 1) zacc += __shfl_xor(zacc, m);
    if ((t & 15) == 0) Zp[(size_t)(part * NB + b) * NN + i0 + rowA] = zacc;

    // ---- stage raw numerator in LDS, coalesced f32 store ----
    __syncthreads();                               // all phase-B reads done
    #pragma unroll
    for (int r = 0; r < 4; ++r) {
        int row = lk * 4 + r;
        hS[row][obase + lr]      = acc0[r];
        hS[row][obase + 16 + lr] = acc1[r];
    }
    __syncthreads();

    int c0 = (t & 15) * 8;
    float* op = num + ((size_t)(part * NB + b) * NN + i0 + rowA) * FOUT + c0;
    *(float4*)op       = *(const float4*)&hS[rowA][c0];
    *(float4*)(op + 4) = *(const float4*)&hS[rowA][c0 + 4];
}

// ---------------- Kernel 3: reduce splits + LayerNorm + GELU --------------
__global__ __launch_bounds__(256) void k_final(const float* __restrict__ num,
                                               const float* __restrict__ Zp,
                                               const float* __restrict__ gamma,
                                               const float* __restrict__ beta,
                                               float* __restrict__ out) {
    int t = threadIdx.x, bi = blockIdx.x;
    int rowA = t >> 5;
    int c0 = (t & 31) * 4;
    size_t gn = (size_t)bi * 8 + rowA;
    int b = (int)(gn >> 11), n = (int)(gn & 2047);

    float Z = 0.f;
    #pragma unroll
    for (int p = 0; p < SPLIT; ++p) Z += Zp[(size_t)(p * NB + b) * NN + n];

    float x[4] = {0.f, 0.f, 0.f, 0.f};
    #pragma unroll
    for (int p = 0; p < SPLIT; ++p) {
        const float* np = num + ((size_t)(p * NB + b) * NN + n) * FOUT + c0;
        float4 v0 = *(const float4*)np;
        x[0] += v0.x; x[1] += v0.y; x[2] += v0.z; x[3] += v0.w;
    }
    float rz = 1.f / Z;
    #pragma unroll
    for (int i = 0; i < 4; ++i) x[i] *= rz;

    float sm = 0.f, sq = 0.f;
    #pragma unroll
    for (int i = 0; i < 4; ++i) { sm += x[i]; sq += x[i] * x[i]; }
    #pragma unroll
    for (int m = 1; m < 32; m <<= 1) {
        sm += __shfl_xor(sm, m);
        sq += __shfl_xor(sq, m);
    }
    float mu  = sm * (1.f / 128.f);
    float var = sq * (1.f / 128.f) - mu * mu;
    float rs  = rsqrtf(var + 1e-5f);
    float4 g0 = *(const float4*)(gamma + c0);
    float4 e0 = *(const float4*)(beta + c0);
    float gg[4] = {g0.x, g0.y, g0.z, g0.w};
    float bb[4] = {e0.x, e0.y, e0.z, e0.w};
    float y[4];
    #pragma unroll
    for (int i = 0; i < 4; ++i) {
        float v = (x[i] - mu) * rs * gg[i] + bb[i];
        y[i] = 0.5f * v * (1.f + erff(v * 0.70710678118f));
    }
    float* op = out + gn * FOUT + c0;
    *(float4*)op = make_float4(y[0], y[1], y[2], y[3]);
}

// ---------------- launcher ----------------
extern "C" void kernel_launch(void* const* d_in, const int* in_sizes, int n_in,
                              void* d_out, int out_size, void* d_ws, size_t ws_size,
                              hipStream_t stream) {
    const float* h     = (const float*)d_in[0];
    const int*   adj   = (const int*)d_in[1];
    const float* W     = (const float*)d_in[2];
    const float* a     = (const float*)d_in[3];
    const float* gamma = (const float*)d_in[4];
    const float* beta  = (const float*)d_in[5];
    float* out = (float*)d_out;

    char* ws = (char*)d_ws;
    unsigned short* WT  = (unsigned short*)ws;                       // 64 KiB
    unsigned short* WhT = (unsigned short*)(ws + (1u << 16));        // 2 MiB
    float* s1 = (float*)(ws + 2162688);                              // 32 KiB
    float* s2 = (float*)(ws + 2195456);                              // 32 KiB
    float* Zp = (float*)(ws + 2228224);                              // 128 KiB
    float* num = (float*)(ws + 2359296);                             // 16 MiB

    hipLaunchKernelGGL(k_wt,        dim3(128),  dim3(256), 0, stream, W, WT);
    hipLaunchKernelGGL(k_wh,        dim3(512),  dim3(256), 0, stream, h, a, WT, WhT, s1, s2);
    hipLaunchKernelGGL(k_attn_part, dim3(2048), dim3(256), 0, stream, adj, WhT, s1, s2, num, Zp);
    hipLaunchKernelGGL(k_final,     dim3(1024), dim3(256), 0, stream, num, Zp, gamma, beta, out);
}

// Round 8
// 55.556 us; speedup vs baseline: 1.0861x; 1.0861x over previous
//
#include <hip/hip_runtime.h>
#include <hip/hip_bf16.h>

typedef __attribute__((ext_vector_type(8))) short bf16x8;
typedef __attribute__((ext_vector_type(4))) float f32x4;

#define NB   4
#define NN   2048
#define FIN  256
#define FOUT 128
#define SPLIT 4
#define JCH  (NN / SPLIT)      // 512 j per block
#define NSTEP (JCH / 64)       // 8 steps of 64 j
#define ITILE 32               // i-rows per attention block

__device__ __forceinline__ unsigned short f2bf(float f) {
    unsigned int u = __builtin_bit_cast(unsigned int, f);
    u += 0x7fffu + ((u >> 16) & 1u);
    return (unsigned short)(u >> 16);
}

// ---------------- Kernel 0: WT[o][k] bf16 from W[k][o] f32 ----------------
__global__ __launch_bounds__(256) void k_wt(const float* __restrict__ W,
                                            unsigned short* __restrict__ WT) {
    int idx = blockIdx.x * 256 + threadIdx.x;
    int k = idx & 255, o = idx >> 8;
    WT[idx] = f2bf(W[k * FOUT + o]);
}

// ---------------- Kernel 0b: adj -> packed nibble words (64 MB -> 2 MB) ---
// Pure stream: one wave per adj row; 8 independent int4 loads/lane (16 B),
// wave-local LDS byte repack (no barrier), coalesced dword stores.
// Output: nbw[row][d] bits [4c+i] = adj[row][32d + 4c + i] > 0.
__global__ __launch_bounds__(256) void k_nib(const int* __restrict__ adj,
                                             unsigned int* __restrict__ nbw) {
    __shared__ unsigned char sh[4][512];
    int t = threadIdx.x, w = t >> 6, l = t & 63;
    size_t wg = (size_t)blockIdx.x * 4 + w;        // 8192 waves = 8192 rows
    const int4* base = (const int4*)adj + wg * 512;
    int4 v[8];
    #pragma unroll
    for (int c = 0; c < 8; ++c) v[c] = base[c * 64 + l];   // 8 KB/wave in flight
    #pragma unroll
    for (int c = 0; c < 8; ++c) {
        unsigned char nb = (unsigned char)((v[c].x > 0) | ((v[c].y > 0) << 1) |
                                           ((v[c].z > 0) << 2) | ((v[c].w > 0) << 3));
        sh[w][c * 64 + l] = nb;
    }
    asm volatile("s_waitcnt lgkmcnt(0)" ::: "memory");      // wave-local LDS
    uint2 u = *(const uint2*)&sh[w][l * 8];
    unsigned int lo = (u.x & 0xFu) | ((u.x >> 4) & 0xF0u) |
                      ((u.x >> 8) & 0xF00u) | ((u.x >> 12) & 0xF000u);
    unsigned int hi = (u.y & 0xFu) | ((u.y >> 4) & 0xF0u) |
                      ((u.y >> 8) & 0xF00u) | ((u.y >> 12) & 0xF000u);
    nbw[wg * 64 + l] = lo | (hi << 16);
}

// ---------------- Kernel 1: Wh = h@W (MFMA), writes WhT bf16 + s1,s2 ------
__global__ __launch_bounds__(256) void k_wh(const float* __restrict__ h,
                                            const float* __restrict__ a,
                                            const unsigned short* __restrict__ WT,
                                            unsigned short* __restrict__ WhT,
                                            float* __restrict__ s1,
                                            float* __restrict__ s2) {
    __shared__ unsigned short hs[16][264];
    __shared__ float s1w[4][16], s2w[4][16];
    int t = threadIdx.x, blk = blockIdx.x;
    int nglob0 = blk * 16;
    int b = nglob0 >> 11;

    const float4* h4 = (const float4*)h + (size_t)blk * 1024;
    #pragma unroll
    for (int i = 0; i < 4; ++i) {
        int idx = i * 256 + t;
        float4 v = h4[idx];
        int row = idx >> 6, c4 = (idx & 63) * 4;
        unsigned int lo = (unsigned int)f2bf(v.x) | ((unsigned int)f2bf(v.y) << 16);
        unsigned int hi = (unsigned int)f2bf(v.z) | ((unsigned int)f2bf(v.w) << 16);
        *(uint2*)&hs[row][c4] = make_uint2(lo, hi);
    }
    __syncthreads();

    int w = t >> 6, l = t & 63, lr = l & 15, lk = l >> 4;
    float a1v[2], a2v[2];
    #pragma unroll
    for (int j = 0; j < 2; ++j) {
        a1v[j] = a[(w * 2 + j) * 16 + lr];
        a2v[j] = a[FOUT + (w * 2 + j) * 16 + lr];
    }
    f32x4 acc[2] = {{0.f,0.f,0.f,0.f},{0.f,0.f,0.f,0.f}};

    #pragma unroll
    for (int kk = 0; kk < 8; ++kk) {
        int k0 = kk * 32;
        bf16x8 af = *(const bf16x8*)&hs[lr][k0 + lk * 8];
        #pragma unroll
        for (int j = 0; j < 2; ++j) {
            bf16x8 bf = *(const bf16x8*)(WT + ((w * 2 + j) * 16 + lr) * 256 + k0 + lk * 8);
            acc[j] = __builtin_amdgcn_mfma_f32_16x16x32_bf16(af, bf, acc[j], 0, 0, 0);
        }
    }

    int nn0 = (nglob0 & 2047) + lk * 4;
    float v1[4] = {0.f,0.f,0.f,0.f}, v2[4] = {0.f,0.f,0.f,0.f};
    #pragma unroll
    for (int j = 0; j < 2; ++j) {
        float x0 = acc[j][0], x1 = acc[j][1], x2 = acc[j][2], x3 = acc[j][3];
        ushort4 pk;
        pk.x = f2bf(x0); pk.y = f2bf(x1); pk.z = f2bf(x2); pk.w = f2bf(x3);
        *(ushort4*)(WhT + (size_t)(b * FOUT + (w * 2 + j) * 16 + lr) * NN + nn0) = pk;
        v1[0] += x0 * a1v[j]; v1[1] += x1 * a1v[j]; v1[2] += x2 * a1v[j]; v1[3] += x3 * a1v[j];
        v2[0] += x0 * a2v[j]; v2[1] += x1 * a2v[j]; v2[2] += x2 * a2v[j]; v2[3] += x3 * a2v[j];
    }
    #pragma unroll
    for (int m = 1; m < 16; m <<= 1) {
        #pragma unroll
        for (int r = 0; r < 4; ++r) {
            v1[r] += __shfl_xor(v1[r], m);
            v2[r] += __shfl_xor(v2[r], m);
        }
    }
    if (lr == 0) {
        #pragma unroll
        for (int r = 0; r < 4; ++r) {
            s1w[w][lk * 4 + r] = v1[r];
            s2w[w][lk * 4 + r] = v2[r];
        }
    }
    __syncthreads();
    if (t < 16) {
        s1[nglob0 + t] = s1w[0][t] + s1w[1][t] + s1w[2][t] + s1w[3][t];
        s2[nglob0 + t] = s2w[0][t] + s2w[1][t] + s2w[2][t] + s2w[3][t];
    }
}

// ---------------- Kernel 2: partial attention, global-free main loop ------
// 1024 blocks x 512 thr; block: 32 i-rows x 512 j; 8 waves each own 16 o.
// ALL WhT B-fragments preloaded to registers (16 x bf16x8, static idx);
// nib words + s2 staged to LDS once. Loop: LDS + VALU + MFMA only.
__global__ __launch_bounds__(512) void k_attn_part(const unsigned int* __restrict__ nbw,
                                                   const unsigned short* __restrict__ WhT,
                                                   const float* __restrict__ s1,
                                                   const float* __restrict__ s2,
                                                   float* __restrict__ num,
                                                   float* __restrict__ Zp) {
    __shared__ unsigned int nibW[ITILE][16];       // 32 rows x 512 bits
    __shared__ float s2S[JCH];
    __shared__ unsigned short Ps[2][ITILE][72];    // P tile bf16, 2 slots
    __shared__ float hS[ITILE][132];

    int t = threadIdx.x, w = t >> 6, l = t & 63, lr = l & 15, lk = l >> 4;
    int bi = blockIdx.x;
    int part = bi >> 8;                            // 0..3
    int rem  = bi & 255;
    int b    = rem >> 6;
    int i0   = (rem & 63) * ITILE;
    int j0   = part * JCH;
    int rowA = t >> 4, kA = (t & 15) * 4;

    // ---- stage nib words (1024 dwords) + s2 chunk (2 KB) ----
    {
        const unsigned int* nb = nbw + ((size_t)(b * NN) + i0) * 64 + part * 16;
        int r0 = t >> 5, c = t & 31;               // 32 dwords per row window? no: 16
        // 32 rows x 16 dwords = 512 dwords; thread t<512 loads exactly one
        int rr = t >> 4, cc = t & 15;
        nibW[rr][cc] = nb[(size_t)rr * 64 + cc];
        (void)r0; (void)c;
        if (t < 128) ((float4*)s2S)[t] = ((const float4*)(s2 + b * NN + j0))[t];
    }
    float s1r = s1[b * NN + i0 + rowA];

    // ---- preload ALL B-fragments to registers (loop-invariant) ----
    const unsigned short* Bb = WhT + ((size_t)(b * FOUT) + w * 16 + lr) * NN + j0 + lk * 8;
    bf16x8 bf[NSTEP][2];
    #pragma unroll
    for (int s = 0; s < NSTEP; ++s) {
        bf[s][0] = *(const bf16x8*)(Bb + s * 64);
        bf[s][1] = *(const bf16x8*)(Bb + s * 64 + 32);
    }

    f32x4 acc[2] = {{0.f,0.f,0.f,0.f},{0.f,0.f,0.f,0.f}};
    float zacc = 0.f;

    __syncthreads();                               // nibW/s2S visible (drains bf loads once)

    #pragma unroll
    for (int s = 0; s < NSTEP; ++s) {
        const int slot = s & 1;
        // ---- phase A: build P tile (32 x 64) from LDS nibbles + s2 ----
        {
            unsigned int word = nibW[rowA][s * 2 + ((t >> 3) & 1)];
            unsigned int nib  = (word >> (4 * (t & 7))) & 0xFu;
            float4 svc = *(const float4*)&s2S[s * 64 + kA];
            float ss[4] = {svc.x, svc.y, svc.z, svc.w};
            unsigned short u[4];
            #pragma unroll
            for (int i = 0; i < 4; ++i) {
                float tt  = s1r + ss[i];
                float lrl = fmaxf(tt, 0.2f * tt);  // LeakyReLU
                float pp  = ((nib >> i) & 1u) ? __expf(lrl) : 0.f;
                zacc += pp;
                u[i] = f2bf(pp);
            }
            unsigned int lo = (unsigned int)u[0] | ((unsigned int)u[1] << 16);
            unsigned int hi = (unsigned int)u[2] | ((unsigned int)u[3] << 16);
            *(uint2*)&Ps[slot][rowA][kA] = make_uint2(lo, hi);
        }
        asm volatile("s_waitcnt lgkmcnt(0)" ::: "memory");
        __builtin_amdgcn_s_barrier();
        __builtin_amdgcn_sched_barrier(0);

        // ---- phase B: 4 MFMAs, B from registers ----
        #pragma unroll
        for (int hh = 0; hh < 2; ++hh) {
            bf16x8 pa0 = *(const bf16x8*)&Ps[slot][hh * 16 + lr][lk * 8];
            bf16x8 pa1 = *(const bf16x8*)&Ps[slot][hh * 16 + lr][32 + lk * 8];
            acc[hh] = __builtin_amdgcn_mfma_f32_16x16x32_bf16(pa0, bf[s][0], acc[hh], 0, 0, 0);
            acc[hh] = __builtin_amdgcn_mfma_f32_16x16x32_bf16(pa1, bf[s][1], acc[hh], 0, 0, 0);
        }
    }

    // ---- Z partial reduction (16 threads per row) ----
    #pragma unroll
    for (int m = 1; m < 16; m <<= 1) zacc += __shfl_xor(zacc, m);
    if ((t & 15) == 0) Zp[(size_t)(part * NB + b) * NN + i0 + rowA] = zacc;

    // ---- stage raw numerator in LDS, coalesced f32 store ----
    __syncthreads();
    #pragma unroll
    for (int hh = 0; hh < 2; ++hh)
        #pragma unroll
        for (int r = 0; r < 4; ++r)
            hS[hh * 16 + lk * 4 + r][w * 16 + lr] = acc[hh][r];
    __syncthreads();

    int c0 = (t & 15) * 8;
    float* op = num + ((size_t)(part * NB + b) * NN + i0 + rowA) * FOUT + c0;
    *(float4*)op       = *(const float4*)&hS[rowA][c0];
    *(float4*)(op + 4) = *(const float4*)&hS[rowA][c0 + 4];
}

// ---------------- Kernel 3: reduce splits + LayerNorm + GELU --------------
__global__ __launch_bounds__(256) void k_final(const float* __restrict__ num,
                                               const float* __restrict__ Zp,
                                               const float* __restrict__ gamma,
                                               const float* __restrict__ beta,
                                               float* __restrict__ out) {
    int t = threadIdx.x, bi = blockIdx.x;
    int rowA = t >> 5;
    int c0 = (t & 31) * 4;
    size_t gn = (size_t)bi * 8 + rowA;
    int b = (int)(gn >> 11), n = (int)(gn & 2047);

    float Z = 0.f;
    #pragma unroll
    for (int p = 0; p < SPLIT; ++p) Z += Zp[(size_t)(p * NB + b) * NN + n];

    float x[4] = {0.f, 0.f, 0.f, 0.f};
    #pragma unroll
    for (int p = 0; p < SPLIT; ++p) {
        const float* np = num + ((size_t)(p * NB + b) * NN + n) * FOUT + c0;
        float4 v0 = *(const float4*)np;
        x[0] += v0.x; x[1] += v0.y; x[2] += v0.z; x[3] += v0.w;
    }
    float rz = 1.f / Z;
    #pragma unroll
    for (int i = 0; i < 4; ++i) x[i] *= rz;

    float sm = 0.f, sq = 0.f;
    #pragma unroll
    for (int i = 0; i < 4; ++i) { sm += x[i]; sq += x[i] * x[i]; }
    #pragma unroll
    for (int m = 1; m < 32; m <<= 1) {
        sm += __shfl_xor(sm, m);
        sq += __shfl_xor(sq, m);
    }
    float mu  = sm * (1.f / 128.f);
    float var = sq * (1.f / 128.f) - mu * mu;
    float rs  = rsqrtf(var + 1e-5f);
    float4 g0 = *(const float4*)(gamma + c0);
    float4 e0 = *(const float4*)(beta + c0);
    float gg[4] = {g0.x, g0.y, g0.z, g0.w};
    float bb[4] = {e0.x, e0.y, e0.z, e0.w};
    float y[4];
    #pragma unroll
    for (int i = 0; i < 4; ++i) {
        float v = (x[i] - mu) * rs * gg[i] + bb[i];
        y[i] = 0.5f * v * (1.f + erff(v * 0.70710678118f));
    }
    float* op = out + gn * FOUT + c0;
    *(float4*)op = make_float4(y[0], y[1], y[2], y[3]);
}

// ---------------- launcher ----------------
extern "C" void kernel_launch(void* const* d_in, const int* in_sizes, int n_in,
                              void* d_out, int out_size, void* d_ws, size_t ws_size,
                              hipStream_t stream) {
    const float* h     = (const float*)d_in[0];
    const int*   adj   = (const int*)d_in[1];
    const float* W     = (const float*)d_in[2];
    const float* a     = (const float*)d_in[3];
    const float* gamma = (const float*)d_in[4];
    const float* beta  = (const float*)d_in[5];
    float* out = (float*)d_out;

    char* ws = (char*)d_ws;
    unsigned short* WT  = (unsigned short*)ws;                       // 64 KiB
    unsigned short* WhT = (unsigned short*)(ws + (1u << 16));        // 2 MiB
    float* s1 = (float*)(ws + 2162688);                              // 32 KiB
    float* s2 = (float*)(ws + 2195456);                              // 32 KiB
    float* Zp = (float*)(ws + 2228224);                              // 128 KiB
    float* num = (float*)(ws + 2359296);                             // 16 MiB
    unsigned int* nbw = (unsigned int*)(ws + 19136512);              // 2 MiB

    hipLaunchKernelGGL(k_wt,        dim3(128),  dim3(256), 0, stream, W, WT);
    hipLaunchKernelGGL(k_nib,       dim3(2048), dim3(256), 0, stream, adj, nbw);
    hipLaunchKernelGGL(k_wh,        dim3(512),  dim3(256), 0, stream, h, a, WT, WhT, s1, s2);
    hipLaunchKernelGGL(k_attn_part, dim3(1024), dim3(512), 0, stream, nbw, WhT, s1, s2, num, Zp);
    hipLaunchKernelGGL(k_final,     dim3(1024), dim3(256), 0, stream, num, Zp, gamma, beta, out);
}